// Round 1
// baseline (800.703 us; speedup 1.0000x reference)
//
#include <hip/hip_runtime.h>
#include <stdint.h>

#define NROW 100000
#define DDIM 512
#define NPAIR 528
#define PK 544            // pairs padded to 17*32
#define KTILES 17
#define NBLK_B 1563       // ceil(100000/64)
#define GAMMA 0.01f
#define ALPHA 1.0f
#define TOLR 1e-6f
#define GUESS 0.999f

using f32x4  = __attribute__((ext_vector_type(4))) float;
using s16x8  = __attribute__((ext_vector_type(8))) short;
using us16x4 = __attribute__((ext_vector_type(4))) unsigned short;
typedef unsigned short ushort_t;
typedef unsigned int   uint_t;

// ws byte offsets
#define WS_XMUU   0          // 32 f32
#define WS_XCU    128        // 32 f32
#define WS_MUN    256        // 1 f32
#define WS_CHANGE 512        // 512 f32
#define WS_UB     4096       // 48*512 bf16 (col-major U_ext: col32=z_mu, 33..47=0)
#define WS_VB     53248      // 512*544 bf16 (Vb[d*544+p], pad 0)
#define WS_COORD  1048576    // N*32 f32
#define WS_KSC    13848576   // N f32

__device__ __forceinline__ ushort_t f2bf(float x) {
    uint_t u = __builtin_bit_cast(uint_t, x);
    u += 0x7fffu + ((u >> 16) & 1u);          // RNE
    return (ushort_t)(u >> 16);
}

// ---------------- kernel A: scalars + bf16 pre-pack ----------------
__global__ __launch_bounds__(256) void kernelA(const float* __restrict__ U,
                                               const float* __restrict__ V,
                                               const float* __restrict__ zmu,
                                               const float* __restrict__ xc,
                                               char* __restrict__ ws) {
    int t = threadIdx.x;
    if (blockIdx.x == 0) {
        __shared__ float redMu[8][32], redC[8][32], redN[8];
        __shared__ float w_s[32];
        int k = t & 31, g = t >> 5;
        float smu = 0.f, sc = 0.f, sn = 0.f;
        for (int d = g * 64; d < g * 64 + 64; ++d) {
            float u = U[d * 32 + k];
            float zm = zmu[d];
            smu += zm * u;
            sc  += xc[d] * u;
            if (k == 0) sn += zm * zm;
        }
        redMu[g][k] = smu; redC[g][k] = sc;
        if (k == 0) redN[g] = sn;
        __syncthreads();
        float* xmuU = (float*)(ws + WS_XMUU);
        float* xcU  = (float*)(ws + WS_XCU);
        if (t < 32) {
            float a = 0.f, b = 0.f;
            for (int g2 = 0; g2 < 8; ++g2) { a += redMu[g2][t]; b += redC[g2][t]; }
            xmuU[t] = a; xcU[t] = b; w_s[t] = b - a;
        }
        if (t == 0) {
            float m = 0.f;
            for (int g2 = 0; g2 < 8; ++g2) m += redN[g2];
            *(float*)(ws + WS_MUN) = m;
        }
        __syncthreads();
        float* change = (float*)(ws + WS_CHANGE);
        for (int d = t; d < DDIM; d += 256) {
            float s = 0.f;
            #pragma unroll
            for (int k2 = 0; k2 < 32; ++k2) s += U[d * 32 + k2] * w_s[k2];
            change[d] = xc[d] - zmu[d] - s;
        }
    } else {
        int b = blockIdx.x - 1;  // 0..127
        ushort_t* Vb = (ushort_t*)(ws + WS_VB);
        for (int i = b * 256 + t; i < DDIM * PK; i += 128 * 256) {
            int d = i / PK, p = i - d * PK;
            float v = (p < NPAIR) ? V[d * NPAIR + p] : 0.f;
            Vb[i] = f2bf(v);
        }
        ushort_t* Ub = (ushort_t*)(ws + WS_UB);
        for (int i = b * 256 + t; i < 48 * DDIM; i += 128 * 256) {
            int c = i >> 9, d = i & 511;
            float v = (c < 32) ? U[d * 32 + c] : ((c == 32) ? zmu[d] : 0.f);
            Ub[i] = f2bf(v);
        }
    }
}

// ---------------- kernel B: ZU, norms, secant -> coord/kscale ----------------
#define ZB_STRIDE 520   // 512 + 8 pad, keeps 16B align, 2-way-free banks
__global__ __launch_bounds__(256) void kernelB(const float* __restrict__ Z,
                                               const int* __restrict__ ci,
                                               char* __restrict__ ws) {
    __shared__ ushort_t zb[64 * ZB_STRIDE];
    __shared__ float zu[64 * 49];
    __shared__ float rowss[64][4];
    __shared__ int   cidx[64];
    __shared__ float xmuU_s[32], xcU_s[32];

    int t = threadIdx.x;
    int rowBase = blockIdx.x * 64;
    if (t < 64) {
        int r = rowBase + t;
        cidx[t] = (r < NROW) ? ci[r] : 0;
    } else if (t < 96) {
        xmuU_s[t - 64] = ((const float*)(ws + WS_XMUU))[t - 64];
    } else if (t < 128) {
        xcU_s[t - 96] = ((const float*)(ws + WS_XCU))[t - 96];
    }
    __syncthreads();

    // stage Z tile (coalesced f32 -> bf16 LDS)
    for (int i = t; i < 64 * 128; i += 256) {
        int row = i >> 7, c4 = i & 127;
        ushort_t* dst = &zb[row * ZB_STRIDE + c4 * 4];
        if (rowBase + row < NROW) {
            const float4 v = ((const float4*)(Z + (size_t)cidx[row] * DDIM))[c4];
            *(us16x4*)dst = (us16x4){f2bf(v.x), f2bf(v.y), f2bf(v.z), f2bf(v.w)};
        } else {
            *(us16x4*)dst = (us16x4){0, 0, 0, 0};
        }
    }
    __syncthreads();

    // ZU_ext GEMM: wave w = row-tile w (16 rows), 3 col-tiles (48 cols, 33 used)
    {
        int wv = t >> 6, lane = t & 63;
        int m = lane & 15, quad = lane >> 4;
        const ushort_t* Ub = (const ushort_t*)(ws + WS_UB);
        f32x4 acc0 = {0,0,0,0}, acc1 = {0,0,0,0}, acc2 = {0,0,0,0};
        #pragma unroll
        for (int ks = 0; ks < 16; ++ks) {
            s16x8 a  = *(const s16x8*)&zb[(wv * 16 + m) * ZB_STRIDE + ks * 32 + quad * 8];
            s16x8 b0 = *(const s16x8*)&Ub[(0 * 16 + m) * DDIM + ks * 32 + quad * 8];
            s16x8 b1 = *(const s16x8*)&Ub[(1 * 16 + m) * DDIM + ks * 32 + quad * 8];
            s16x8 b2 = *(const s16x8*)&Ub[(2 * 16 + m) * DDIM + ks * 32 + quad * 8];
            acc0 = __builtin_amdgcn_mfma_f32_16x16x32_bf16(a, b0, acc0, 0, 0, 0);
            acc1 = __builtin_amdgcn_mfma_f32_16x16x32_bf16(a, b1, acc1, 0, 0, 0);
            acc2 = __builtin_amdgcn_mfma_f32_16x16x32_bf16(a, b2, acc2, 0, 0, 0);
        }
        #pragma unroll
        for (int r = 0; r < 4; ++r) {   // C/D: col=lane&15, row=quad*4+reg
            int row = wv * 16 + quad * 4 + r;
            zu[row * 49 + 0 + m]  = acc0[r];
            zu[row * 49 + 16 + m] = acc1[r];
            zu[row * 49 + 32 + m] = acc2[r];
        }
    }
    __syncthreads();

    // per-row sumsq(Z) from bf16 tile
    {
        int row = t >> 2, q = t & 3;
        float s = 0.f;
        const uint_t* p = (const uint_t*)&zb[row * ZB_STRIDE + q * 128];
        #pragma unroll 8
        for (int j = 0; j < 64; ++j) {
            uint_t w2 = p[j];
            float a = __builtin_bit_cast(float, (uint_t)(w2 << 16));
            float b = __builtin_bit_cast(float, (uint_t)(w2 & 0xffff0000u));
            s += a * a + b * b;
        }
        rowss[row][q] = s;
    }
    __syncthreads();

    // solve (one thread per row)
    if (t < 64) {
        int grow = rowBase + t;
        float ss   = rowss[t][0] + rowss[t][1] + rowss[t][2] + rowss[t][3];
        float zzmu = zu[t * 49 + 32];
        float mun  = *(const float*)(ws + WS_MUN);
        float Zn2  = ss - 2.f * zzmu + mun;
        float ZUn2 = 0.f;
        float* coordWs = (float*)(ws + WS_COORD) + (size_t)grow * 32;
        #pragma unroll
        for (int k = 0; k < 32; ++k) {
            float zk = zu[t * 49 + k];
            float d1 = zk - xmuU_s[k];
            ZUn2 += d1 * d1;
            if (grow < NROW) coordWs[k] = zk - xcU_s[k];
        }
        float c  = Zn2 - ZUn2;          // ZUperp_norm2
        float eg = __expf(-GAMMA * ZUn2);
        float xm2 = c * GUESS, xm1 = c;
        float t1 = 1.f - ALPHA * eg * __expf(-GAMMA * xm1);
        float f1 = t1 * t1 * xm1 - c;
        float t2 = 1.f - ALPHA * eg * __expf(-GAMMA * xm2);
        float f2 = t2 * t2 * xm2 - c;
        for (int it = 0; it < 100; ++it) {
            float fd = f1 - f2;
            if (fabsf(fd) < TOLR) fd = (fd >= 0.f) ? TOLR : -TOLR;
            float xn = xm1 - f1 * (xm1 - xm2) / fd;
            float step = fabsf(xn - xm1);
            xm2 = xm1; f2 = f1; xm1 = xn;
            float tn = 1.f - ALPHA * eg * __expf(-GAMMA * xm1);
            f1 = tn * tn * xm1 - c;
            if (step < TOLR) break;     // per-row break; diff vs global-done ~ sub-ulp
        }
        if (grow < NROW)
            ((float*)(ws + WS_KSC))[grow] = ALPHA * __expf(-GAMMA * (ZUn2 + xm1));
    }
}

// ---------------- kernel C: H@V^T GEMM + epilogue ----------------
#define HB_STRIDE 552   // 544 + 8 pad
#define CO_STRIDE 36
__global__ __launch_bounds__(256) void kernelC(const float* __restrict__ Z,
                                               const int* __restrict__ ci,
                                               const float* __restrict__ chg,
                                               const ushort_t* __restrict__ Vb,
                                               const float* __restrict__ coordWs,
                                               const float* __restrict__ kscWs,
                                               float* __restrict__ out) {
    __shared__ ushort_t hb[64 * HB_STRIDE];
    __shared__ float coords[64 * CO_STRIDE];
    __shared__ float ksc_s[64];
    __shared__ int   cidx[64];
    __shared__ unsigned char iu0s[PK], iu1s[PK];

    int t = threadIdx.x;
    int rowBase = blockIdx.x * 64;
    int colBase = blockIdx.y * 256;

    if (t < 64) {
        int r = rowBase + t;
        cidx[t]  = (r < NROW) ? ci[r] : 0;
        ksc_s[t] = (r < NROW) ? kscWs[r] : 0.f;
    }
    for (int i = t; i < 64 * 32; i += 256) {
        int row = i >> 5, k = i & 31;
        int r = rowBase + row;
        coords[row * CO_STRIDE + k] = (r < NROW) ? coordWs[(size_t)r * 32 + k] : 0.f;
    }
    for (int tt = t; tt < PK; tt += 256) {  // triu_indices(32) tables
        int a = 0, b = 0;
        if (tt < NPAIR) {
            while (a < 31) {
                int nxt = 32 * (a + 1) - (a + 1) * a / 2;
                if (tt >= nxt) a++; else break;
            }
            int st = 32 * a - a * (a - 1) / 2;
            b = a + (tt - st);
        }
        iu0s[tt] = (unsigned char)a; iu1s[tt] = (unsigned char)b;
    }
    __syncthreads();

    // build H tile (bf16) from coord
    {
        int row = t >> 2, q = t & 3;
        int tt = q * 136, end = tt + 136;
        const float* crow = &coords[row * CO_STRIDE];
        int a = iu0s[tt], b = iu1s[tt];
        float ca = crow[a];
        for (; tt < end; tt += 2) {
            float v0 = 0.f, v1 = 0.f;
            if (tt < NPAIR) {
                v0 = ca * crow[b];
                if (++b >= 32) { ++a; ca = crow[a & 31]; b = a; }
            }
            if (tt + 1 < NPAIR) {
                v1 = ca * crow[b];
                if (++b >= 32) { ++a; ca = crow[a & 31]; b = a; }
            }
            uint_t w2 = (uint_t)f2bf(v0) | ((uint_t)f2bf(v1) << 16);
            *(uint_t*)&hb[row * HB_STRIDE + tt] = w2;
        }
    }
    __syncthreads();

    // K-loop: wave = 4 row-tiles x 4 col-tiles (64 rows x 64 cols)
    int wv = t >> 6, lane = t & 63;
    int m = lane & 15, quad = lane >> 4;
    int wcol = colBase + wv * 64;
    f32x4 acc[4][4];
    #pragma unroll
    for (int i = 0; i < 4; ++i)
        #pragma unroll
        for (int j = 0; j < 4; ++j) acc[i][j] = (f32x4){0, 0, 0, 0};

    #pragma unroll 1
    for (int ks = 0; ks < KTILES; ++ks) {
        s16x8 af[4], bfr[4];
        #pragma unroll
        for (int rt = 0; rt < 4; ++rt)
            af[rt] = *(const s16x8*)&hb[(rt * 16 + m) * HB_STRIDE + ks * 32 + quad * 8];
        #pragma unroll
        for (int ct = 0; ct < 4; ++ct)
            bfr[ct] = *(const s16x8*)&Vb[(size_t)(wcol + ct * 16 + m) * PK + ks * 32 + quad * 8];
        #pragma unroll
        for (int rt = 0; rt < 4; ++rt)
            #pragma unroll
            for (int ct = 0; ct < 4; ++ct)
                acc[rt][ct] = __builtin_amdgcn_mfma_f32_16x16x32_bf16(af[rt], bfr[ct], acc[rt][ct], 0, 0, 0);
    }

    // epilogue: out = Z + kscale*(change + corr)
    #pragma unroll
    for (int ct = 0; ct < 4; ++ct) {
        int d = wcol + ct * 16 + m;
        float chd = chg[d];
        #pragma unroll
        for (int rt = 0; rt < 4; ++rt) {
            #pragma unroll
            for (int r = 0; r < 4; ++r) {
                int row = rt * 16 + quad * 4 + r;
                if (rowBase + row < NROW) {
                    size_t zr = (size_t)cidx[row];
                    float z = Z[zr * DDIM + d];
                    out[zr * DDIM + d] = z + ksc_s[row] * (chd + acc[rt][ct][r]);
                }
            }
        }
    }
}

extern "C" void kernel_launch(void* const* d_in, const int* in_sizes, int n_in,
                              void* d_out, int out_size, void* d_ws, size_t ws_size,
                              hipStream_t stream) {
    const float* Z   = (const float*)d_in[0];
    const float* U   = (const float*)d_in[1];
    const float* V   = (const float*)d_in[2];
    const float* zmu = (const float*)d_in[3];
    const float* xc  = (const float*)d_in[4];
    const int*   ci  = (const int*)d_in[5];
    char* ws = (char*)d_ws;
    float* out = (float*)d_out;

    hipLaunchKernelGGL(kernelA, dim3(129), dim3(256), 0, stream, U, V, zmu, xc, ws);
    hipLaunchKernelGGL(kernelB, dim3(NBLK_B), dim3(256), 0, stream, Z, ci, ws);
    hipLaunchKernelGGL(kernelC, dim3(NBLK_B, 2), dim3(256), 0, stream,
                       Z, ci, (const float*)(ws + WS_CHANGE),
                       (const ushort_t*)(ws + WS_VB),
                       (const float*)(ws + WS_COORD),
                       (const float*)(ws + WS_KSC), out);
}